// Round 3
// baseline (593.775 us; speedup 1.0000x reference)
//
#include <hip/hip_runtime.h>
#include <stdint.h>

typedef unsigned short u16;
typedef unsigned long long u64;
typedef __attribute__((ext_vector_type(8))) short bf16x8;
typedef __attribute__((ext_vector_type(4))) float f32x4;

#define DEV __device__ __forceinline__

DEV u16 f2bf(float f) {
  union { float f; unsigned u; } v; v.f = f;
  unsigned r = (v.u + 0x7fffu + ((v.u >> 16) & 1u)) >> 16;
  return (u16)r;
}

#define GLDS(g, l) __builtin_amdgcn_global_load_lds( \
    (const __attribute__((address_space(1))) void*)(g), \
    (__attribute__((address_space(3))) void*)(l), 16, 0, 0)

#define BAR() __builtin_amdgcn_s_barrier()
#define LGKM0() asm volatile("s_waitcnt lgkmcnt(0)" ::: "memory")
#define VMW(n) asm volatile("s_waitcnt vmcnt(" #n ")" ::: "memory")
#define SCHED0() __builtin_amdgcn_sched_barrier(0)
// inline-asm ds_read_b128: invisible to SIInsertWaitcnts, so the compiler
// cannot re-insert conservative vmcnt(0) drains against the GLDS staging
// (rule #18 / m201).  Correctness carried by LGKM0+SCHED0 before each MFMA.
#define DSR(dst, p) asm volatile("ds_read_b128 %0, %1" \
    : "=v"(dst) : "v"((const __attribute__((address_space(3))) void*)(p)))

// ------- fused weight transpose+cast: [K][N] f32 -> [N][K] bf16, 4 segments --
__global__ __launch_bounds__(256) void k_transpose_all(
    const float* __restrict__ Wqkv, const float* __restrict__ Wout,
    const float* __restrict__ W1, const float* __restrict__ W2,
    u16* __restrict__ WqkvT, u16* __restrict__ WoutT,
    u16* __restrict__ W1T, u16* __restrict__ W2T) {
  int id = blockIdx.x;
  const float* in; u16* out; int K, N, nx, base;
  if (id < 3072)      { in = Wqkv; out = WqkvT; K = 1024; N = 3072; nx = 96;  base = 0; }
  else if (id < 4096) { in = Wout; out = WoutT; K = 1024; N = 1024; nx = 32;  base = 3072; }
  else if (id < 8192) { in = W1;   out = W1T;   K = 1024; N = 4096; nx = 128; base = 4096; }
  else                { in = W2;   out = W2T;   K = 4096; N = 1024; nx = 32;  base = 8192; }
  int seg = id - base, bx = seg % nx, by = seg / nx;
  __shared__ float tile[32][33];
  int tx = threadIdx.x & 31, ty = threadIdx.x >> 5;  // 32 x 8
#pragma unroll
  for (int r = 0; r < 32; r += 8)
    tile[ty + r][tx] = in[(size_t)(by * 32 + ty + r) * N + bx * 32 + tx];
  __syncthreads();
#pragma unroll
  for (int r = 0; r < 32; r += 8)
    out[(size_t)(bx * 32 + ty + r) * K + by * 32 + tx] = f2bf(tile[tx][ty + r]);
}

// ---------------- LayerNorm: x [rows][1024] f32 -> out bf16 ------------------
__global__ __launch_bounds__(256) void k_layernorm(
    const float* __restrict__ x, const float* __restrict__ gamma,
    const float* __restrict__ beta, u16* __restrict__ out) {
  int row = blockIdx.x, t = threadIdx.x;
  const float4 v = ((const float4*)(x + (size_t)row * 1024))[t];
  float sum = v.x + v.y + v.z + v.w;
  float sq = v.x * v.x + v.y * v.y + v.z * v.z + v.w * v.w;
#pragma unroll
  for (int o = 32; o >= 1; o >>= 1) {
    sum += __shfl_down(sum, o);
    sq += __shfl_down(sq, o);
  }
  __shared__ float red[8];
  if ((t & 63) == 0) { red[(t >> 6) * 2] = sum; red[(t >> 6) * 2 + 1] = sq; }
  __syncthreads();
  sum = red[0] + red[2] + red[4] + red[6];
  sq = red[1] + red[3] + red[5] + red[7];
  float mean = sum * (1.0f / 1024.0f);
  float var = sq * (1.0f / 1024.0f) - mean * mean;
  float rstd = rsqrtf(var + 1e-5f);
  float4 g = ((const float4*)gamma)[t];
  float4 b = ((const float4*)beta)[t];
  ushort4 o4;
  o4.x = f2bf(g.x * (v.x - mean) * rstd + b.x);
  o4.y = f2bf(g.y * (v.y - mean) * rstd + b.y);
  o4.z = f2bf(g.z * (v.z - mean) * rstd + b.z);
  o4.w = f2bf(g.w * (v.w - mean) * rstd + b.w);
  ((ushort4*)(out + (size_t)row * 1024))[t] = o4;
}

// ---------------- epilogues (r = M row; c0 = first of 4 consecutive N) -------
struct EpiQKV {  // scatter qkv: Q,K [B*H][S][64] bf16 ; VT [B*H][64][S] bf16
  u16 *Q, *K2, *VT;
  DEV void operator()(int r, int c0, const f32x4& v) const {
    int three = c0 >> 10, h = (c0 >> 6) & 15, hd = c0 & 63;
    int b = r >> 11, s = r & 2047;
    int bh = b * 16 + h;
    ushort4 o;
    o.x = f2bf(v[0]); o.y = f2bf(v[1]); o.z = f2bf(v[2]); o.w = f2bf(v[3]);
    if (three == 0)
      *(ushort4*)&Q[((size_t)bh * 2048 + s) * 64 + hd] = o;
    else if (three == 1)
      *(ushort4*)&K2[((size_t)bh * 2048 + s) * 64 + hd] = o;
    else {
      VT[((size_t)bh * 64 + hd + 0) * 2048 + s] = o.x;
      VT[((size_t)bh * 64 + hd + 1) * 2048 + s] = o.y;
      VT[((size_t)bh * 64 + hd + 2) * 2048 + s] = o.z;
      VT[((size_t)bh * 64 + hd + 3) * 2048 + s] = o.w;
    }
  }
};

struct EpiBiasResid {  // out f32 = v + bias[c] + resid[r*N+c]
  const float* bias; const float* resid; float* out; int N;
  DEV void operator()(int r, int c0, const f32x4& v) const {
    size_t idx = (size_t)r * N + c0;
    float4 bb = *(const float4*)&bias[c0];
    float4 rr = *(const float4*)&resid[idx];
    float4 o;
    o.x = v[0] + bb.x + rr.x; o.y = v[1] + bb.y + rr.y;
    o.z = v[2] + bb.z + rr.z; o.w = v[3] + bb.w + rr.w;
    *(float4*)&out[idx] = o;
  }
};

struct EpiBiasGelu {  // out bf16 = gelu_tanh(v + bias[c])
  const float* bias; u16* out; int N;
  DEV float gelu(float xx) const {
    float u = 0.7978845608f * (xx + 0.044715f * xx * xx * xx);
    float e = __expf(2.0f * u);
    float th = 1.0f - 2.0f / (e + 1.0f);
    return 0.5f * xx * (1.0f + th);
  }
  DEV void operator()(int r, int c0, const f32x4& v) const {
    float4 bb = *(const float4*)&bias[c0];
    ushort4 o;
    o.x = f2bf(gelu(v[0] + bb.x)); o.y = f2bf(gelu(v[1] + bb.y));
    o.z = f2bf(gelu(v[2] + bb.z)); o.w = f2bf(gelu(v[3] + bb.w));
    *(ushort4*)&out[(size_t)r * N + c0] = o;
  }
};

// ---------------- GEMM TN 256x256, 8-phase counted-vmcnt schedule ------------
// A[M,K] bf16 K-contig (M must be 8192), Bt[N,K] bf16 K-contig. BK=64.
// 512 thr = 8 waves (2M x 4N); per-wave 128x64 out, acc[8][4].
// LDS 128 KB: 2 buffers x (A 32KB + B 32KB).  GLDS linear-dest staging with
// inverse-swizzled GLOBAL source; asm ds_read applies the same XOR:
//   LDS(row, slot16B) holds global k-slot (slot ^ (row&7))  -> every
//   ds_read_b128 covers all 32 banks uniformly (8 lanes / 16B slot = b128 floor).
// Per tile T (buf d=T&1), 4 phases (one C-quadrant, 16 MFMA each):
//  q0: read A[d] m0-3 + B[d] n0-1 (12 asm b128); stage A-lo(T+1)->d^1 | bar;lgkm0;sched0;MFMA
//  q1: read B[d] n2-3 (4);                stage A-hi(T+1)->d^1 | bar;lgkm0;sched0;MFMA
//  q2: read A[d] m4-7 (8);                stage B-lo(T+2)->d   | bar;lgkm0;sched0;MFMA
//  q3:                                    stage B-hi(T+2)->d   | bar;MFMA;
//      vmcnt(4) [= the 2 B(T+2) half-tiles just issued]; bar
// vmcnt ledger: end of group T outstanding = B(T+1)4 + A(T+1)4 + B(T+2)4 = 12;
// vmcnt(4) drains exactly what group T+1 reads.  Tail groups drop to vmcnt(0).
// WAR on Bs[dg] barrier-protected: all asm LDBQ reads drain (per-wave LGKM0)
// before the q1-end barrier that precedes STAGE_B issue.
#define STAGE_A(tk, d, h) do { \
  GLDS(gA + (size_t)((h) * 128) * K + (tk) * 64, \
       &As[(d)][((h) * 128) * 64 + t * 8]); \
  GLDS(gA + (size_t)((h) * 128 + 64) * K + (tk) * 64, \
       &As[(d)][((h) * 128 + 64) * 64 + t * 8]); \
} while (0)
#define STAGE_B(tk, d, h) do { \
  GLDS(gB + (size_t)((h) * 128) * K + (tk) * 64, \
       &Bs[(d)][((h) * 128) * 64 + t * 8]); \
  GLDS(gB + (size_t)((h) * 128 + 64) * K + (tk) * 64, \
       &Bs[(d)][((h) * 128 + 64) * 64 + t * 8]); \
} while (0)

#define LDAQ(d_, mh) \
  _Pragma("unroll") for (int mt = 0; mt < 4; ++mt) \
  _Pragma("unroll") for (int kk = 0; kk < 2; ++kk) \
    DSR(af[mt][kk], (const char*)&As[(d_)][0] + \
        ((wm * 128 + (mh) * 64 + mt * 16 + l16) * 128 + \
         ((kk * 64 + quad * 16) ^ swz)))

#define LDBQ(d_, nh) \
  _Pragma("unroll") for (int nt = 0; nt < 2; ++nt) \
  _Pragma("unroll") for (int kk = 0; kk < 2; ++kk) \
    DSR(bf[(nh) * 2 + nt][kk], (const char*)&Bs[(d_)][0] + \
        ((wn * 64 + ((nh) * 2 + nt) * 16 + l16) * 128 + \
         ((kk * 64 + quad * 16) ^ swz)))

#define MM(mh, nh) do { \
  __builtin_amdgcn_s_setprio(1); \
  _Pragma("unroll") for (int mt = 0; mt < 4; ++mt) \
  _Pragma("unroll") for (int nt = 0; nt < 2; ++nt) \
  _Pragma("unroll") for (int kk = 0; kk < 2; ++kk) \
    acc[(mh) * 4 + mt][(nh) * 2 + nt] = \
        __builtin_amdgcn_mfma_f32_16x16x32_bf16( \
            bf[(nh) * 2 + nt][kk], af[mt][kk], \
            acc[(mh) * 4 + mt][(nh) * 2 + nt], 0, 0, 0); \
  __builtin_amdgcn_s_setprio(0); \
} while (0)

#define GROUP(T_, d_) do { \
  const int Tg = (T_); const int dg = (d_); \
  const bool stA = Tg + 1 < NT, stB = Tg + 2 < NT; \
  LDAQ(dg, 0); \
  LDBQ(dg, 0); \
  if (stA) STAGE_A(Tg + 1, (dg) ^ 1, 0); \
  BAR(); LGKM0(); SCHED0(); \
  MM(0, 0); \
  BAR(); \
  LDBQ(dg, 1); \
  if (stA) STAGE_A(Tg + 1, (dg) ^ 1, 1); \
  BAR(); LGKM0(); SCHED0(); \
  MM(0, 1); \
  BAR(); \
  LDAQ(dg, 1); \
  if (stB) STAGE_B(Tg + 2, dg, 0); \
  BAR(); LGKM0(); SCHED0(); \
  MM(1, 1); \
  BAR(); \
  if (stB) STAGE_B(Tg + 2, dg, 1); \
  BAR(); \
  MM(1, 0); \
  if (stB) { VMW(4); } else { VMW(0); } \
  BAR(); \
} while (0)

template <typename Epi>
__global__ __launch_bounds__(512, 2) void k_gemm256(
    const u16* __restrict__ A, const u16* __restrict__ Bt, int K, Epi epi) {
  __shared__ __align__(16) u16 As[2][256 * 64];  // 64 KB
  __shared__ __align__(16) u16 Bs[2][256 * 64];  // 64 KB
  const int t = threadIdx.x;
  int id = blockIdx.x;
  { // bijective XCD swizzle (all our grids are %8==0)
    int nwg = gridDim.x;
    if (!(nwg & 7)) id = (id & 7) * (nwg >> 3) + (id >> 3);
  }
  const int bm = id & 31, bn = id >> 5;  // M fixed = 8192 -> 32 row tiles
  const int lane = t & 63, w = t >> 6;
  const int wm = w >> 2, wn = w & 3;
  const int quad = lane >> 4, l16 = lane & 15;
  const int swz = (l16 & 7) << 4;  // byte XOR for LDS 16B-slot index
  const int NT = K >> 6;           // K in {1024,4096} -> NT in {16,64}, even, >=4
  // staging source: thread t covers row (t>>3), k-slot (t&7)^((t>>3)&7)
  const int srow = t >> 3, sslot = (t & 7) ^ (srow & 7);
  const u16* gA = A + (size_t)(bm * 256 + srow) * K + sslot * 8;
  const u16* gB = Bt + (size_t)(bn * 256 + srow) * K + sslot * 8;

  f32x4 acc[8][4] = {};
  bf16x8 af[4][2], bf[4][2];

  // prologue stream matches steady state: B(0), A(0), B(1); vmcnt(4) leaves
  // only B(1)'s 4 ticks outstanding -> B(0)+A(0) landed before group 0 reads.
  STAGE_B(0, 0, 0); STAGE_B(0, 0, 1);
  STAGE_A(0, 0, 0); STAGE_A(0, 0, 1);
  STAGE_B(1, 1, 0); STAGE_B(1, 1, 1);
  VMW(4);
  BAR();

#pragma unroll 1
  for (int T = 0; T < NT; T += 2) {
    GROUP(T, 0);
    GROUP(T + 1, 1);
  }

  const int r0 = bm * 256 + wm * 128 + l16;
  const int c0 = bn * 256 + wn * 64 + quad * 4;
#pragma unroll
  for (int mt = 0; mt < 8; ++mt)
#pragma unroll
    for (int nt = 0; nt < 4; ++nt)
      epi(r0 + mt * 16, c0 + nt * 16, acc[mt][nt]);
}

// ---------------- causal flash attention (S^T form, no-max online softmax) ---
#define PW 72  // u16 row stride: 144 B; 2-way banks on b128 reads (free)

__global__ __launch_bounds__(256) void k_attn(
    const u16* __restrict__ Qg, const u16* __restrict__ Kg,
    const u16* __restrict__ VTg, u16* __restrict__ ctx) {
  const int bh = blockIdx.x;
  const int qt = 31 - blockIdx.y;  // big blocks first for tail scheduling
  const int b = bh >> 4, h = bh & 15;
  const int t = threadIdx.x, lane = t & 63, w = t >> 6;
  const int quad = lane >> 4, l16 = lane & 15;
  const int q0 = qt * 64;
  __shared__ u16 Qs[64 * PW], Ks[64 * PW], Vs[64 * PW];
  __shared__ u16 Ps[4][16 * PW];
  __shared__ float l_lds[4][16];
  const u16* Qbase = Qg + (size_t)bh * (2048 * 64);
  const u16* Kbase = Kg + (size_t)bh * (2048 * 64);
  const u16* Vbase = VTg + (size_t)bh * (64 * 2048);
#pragma unroll
  for (int j = 0; j < 4; ++j) {
    int ch = t + 256 * j, r = ch >> 4, cc = (ch & 15) * 4;
    *(u64*)&Qs[r * PW + cc] = *(const u64*)(Qbase + (size_t)(q0 + r) * 64 + cc);
  }
  __syncthreads();
  bf16x8 qf0 = *(const bf16x8*)&Qs[(w * 16 + l16) * PW + quad * 8];
  bf16x8 qf1 = *(const bf16x8*)&Qs[(w * 16 + l16) * PW + 32 + quad * 8];
  const int qrow = q0 + w * 16 + l16;  // one q-row per lane
  const float c1 = 0.18033688011f;     // (1/8) * log2(e)
  float lsum = 0.f;
  f32x4 acco[4] = {};
  for (int kt = 0; kt <= qt; ++kt) {
    const int k0 = kt * 64;
    __syncthreads();
#pragma unroll
    for (int j = 0; j < 4; ++j) {
      int ch = t + 256 * j, r = ch >> 4, cc = (ch & 15) * 4;
      *(u64*)&Ks[r * PW + cc] =
          *(const u64*)(Kbase + (size_t)(k0 + r) * 64 + cc);
      *(u64*)&Vs[r * PW + cc] =
          *(const u64*)(Vbase + (size_t)r * 2048 + k0 + cc);
    }
    __syncthreads();
    f32x4 sacc[4] = {};
#pragma unroll
    for (int kk = 0; kk < 2; ++kk) {
      bf16x8 qf = kk ? qf1 : qf0;
#pragma unroll
      for (int nt = 0; nt < 4; ++nt) {
        bf16x8 kf = *(const bf16x8*)&Ks[(nt * 16 + l16) * PW + kk * 32 + quad * 8];
        sacc[nt] = __builtin_amdgcn_mfma_f32_16x16x32_bf16(kf, qf, sacc[nt], 0, 0, 0);
      }
    }
    const bool diag = (kt == qt);
    float ls = 0.f;
#pragma unroll
    for (int nt = 0; nt < 4; ++nt) {
      ushort4 o;
#pragma unroll
      for (int reg = 0; reg < 4; ++reg) {
        float p = __builtin_amdgcn_exp2f(sacc[nt][reg] * c1);  // bounded scores
        if (diag && (k0 + nt * 16 + quad * 4 + reg > qrow)) p = 0.f;
        ls += p;
        (&o.x)[reg] = f2bf(p);
      }
      *(ushort4*)&Ps[w][l16 * PW + nt * 16 + quad * 4] = o;  // P^T -> A-layout
    }
    ls += __shfl_xor(ls, 16);
    ls += __shfl_xor(ls, 32);
    lsum += ls;
#pragma unroll
    for (int kk = 0; kk < 2; ++kk) {
      bf16x8 pf = *(const bf16x8*)&Ps[w][l16 * PW + kk * 32 + quad * 8];
#pragma unroll
      for (int nt = 0; nt < 4; ++nt) {
        bf16x8 vf = *(const bf16x8*)&Vs[(nt * 16 + l16) * PW + kk * 32 + quad * 8];
        acco[nt] = __builtin_amdgcn_mfma_f32_16x16x32_bf16(pf, vf, acco[nt], 0, 0, 0);
      }
    }
  }
  if (quad == 0) l_lds[w][l16] = lsum;  // same-wave DS ops are ordered
  float4 lv = *(const float4*)&l_lds[w][quad * 4];
  float inv[4];
  inv[0] = 1.0f / lv.x; inv[1] = 1.0f / lv.y;
  inv[2] = 1.0f / lv.z; inv[3] = 1.0f / lv.w;
#pragma unroll
  for (int nt = 0; nt < 4; ++nt)
#pragma unroll
    for (int reg = 0; reg < 4; ++reg) {
      float o = acco[nt][reg] * inv[reg];
      int q = q0 + w * 16 + quad * 4 + reg;
      ctx[((size_t)(b * 2048 + q)) * 1024 + h * 64 + nt * 16 + l16] = f2bf(o);
    }
}

// ---------------- orchestration ----------------------------------------------
extern "C" void kernel_launch(void* const* d_in, const int* in_sizes, int n_in,
                              void* d_out, int out_size, void* d_ws, size_t ws_size,
                              hipStream_t stream) {
  (void)in_sizes; (void)n_in; (void)out_size; (void)ws_size;
  const float* x    = (const float*)d_in[0];
  const float* Wqkv = (const float*)d_in[1];
  const float* Wout = (const float*)d_in[2];
  const float* bout = (const float*)d_in[3];
  const float* W1   = (const float*)d_in[4];
  const float* b1   = (const float*)d_in[5];
  const float* W2   = (const float*)d_in[6];
  const float* b2   = (const float*)d_in[7];
  const float* g1   = (const float*)d_in[8];
  const float* s1   = (const float*)d_in[9];
  const float* g2   = (const float*)d_in[10];
  const float* s2   = (const float*)d_in[11];

  char* ws = (char*)d_ws;
  u16*   WqkvT = (u16*)(ws + 0);           //  6291456 B
  u16*   WoutT = (u16*)(ws + 6291456);     //  2097152
  u16*   W1T   = (u16*)(ws + 8388608);     //  8388608
  u16*   W2T   = (u16*)(ws + 16777216);    //  8388608
  float* x1    = (float*)(ws + 25165824);  // 33554432
  u16*   h12   = (u16*)(ws + 58720256);    // 16777216  (h1, later h2)
  u16*   Qb    = (u16*)(ws + 75497472);    // 16777216
  u16*   Kb    = (u16*)(ws + 92274688);    // 16777216
  u16*   VTb   = (u16*)(ws + 109051904);   // 16777216
  u16*   ctx   = (u16*)(ws + 125829120);   // 16777216  -> total 142606336
  u16*   a1    = (u16*)(ws + 75497472);    // 67108864, aliases Q..ctx (dead)

  k_transpose_all<<<12288, 256, 0, stream>>>(Wqkv, Wout, W1, W2,
                                             WqkvT, WoutT, W1T, W2T);

  k_layernorm<<<8192, 256, 0, stream>>>(x, g1, s1, h12);
  // grids: 32 M-tiles x (N/256) col-tiles, all divisible by 8 (XCD swizzle ok)
  k_gemm256<<<384, 512, 0, stream>>>(h12, WqkvT, 1024, EpiQKV{Qb, Kb, VTb});
  k_attn<<<dim3(64, 32), 256, 0, stream>>>(Qb, Kb, VTb, ctx);
  k_gemm256<<<128, 512, 0, stream>>>(ctx, WoutT, 1024,
                                     EpiBiasResid{bout, x, x1, 1024});
  k_layernorm<<<8192, 256, 0, stream>>>(x1, g2, s2, h12);
  k_gemm256<<<512, 512, 0, stream>>>(h12, W1T, 1024, EpiBiasGelu{b1, a1, 4096});
  k_gemm256<<<128, 512, 0, stream>>>(a1, W2T, 4096,
                                     EpiBiasResid{b2, x1, (float*)d_out, 1024});
}

// Round 5
// 535.766 us; speedup vs baseline: 1.1083x; 1.1083x over previous
//
#include <hip/hip_runtime.h>
#include <stdint.h>

typedef unsigned short u16;
typedef unsigned long long u64;
typedef __attribute__((ext_vector_type(8))) short bf16x8;
typedef __attribute__((ext_vector_type(4))) float f32x4;

#define DEV __device__ __forceinline__

DEV u16 f2bf(float f) {
  union { float f; unsigned u; } v; v.f = f;
  unsigned r = (v.u + 0x7fffu + ((v.u >> 16) & 1u)) >> 16;
  return (u16)r;
}

#define GLDS(g, l) __builtin_amdgcn_global_load_lds( \
    (const __attribute__((address_space(1))) void*)(g), \
    (__attribute__((address_space(3))) void*)(l), 16, 0, 0)

#define BAR() __builtin_amdgcn_s_barrier()
#define VMW(n) asm volatile("s_waitcnt vmcnt(" #n ")" ::: "memory")
#define SCHED0() __builtin_amdgcn_sched_barrier(0)

// ------- fused weight transpose+cast: [K][N] f32 -> [N][K] bf16, 4 segments --
__global__ __launch_bounds__(256) void k_transpose_all(
    const float* __restrict__ Wqkv, const float* __restrict__ Wout,
    const float* __restrict__ W1, const float* __restrict__ W2,
    u16* __restrict__ WqkvT, u16* __restrict__ WoutT,
    u16* __restrict__ W1T, u16* __restrict__ W2T) {
  int id = blockIdx.x;
  const float* in; u16* out; int K, N, nx, base;
  if (id < 3072)      { in = Wqkv; out = WqkvT; K = 1024; N = 3072; nx = 96;  base = 0; }
  else if (id < 4096) { in = Wout; out = WoutT; K = 1024; N = 1024; nx = 32;  base = 3072; }
  else if (id < 8192) { in = W1;   out = W1T;   K = 1024; N = 4096; nx = 128; base = 4096; }
  else                { in = W2;   out = W2T;   K = 4096; N = 1024; nx = 32;  base = 8192; }
  int seg = id - base, bx = seg % nx, by = seg / nx;
  __shared__ float tile[32][33];
  int tx = threadIdx.x & 31, ty = threadIdx.x >> 5;  // 32 x 8
#pragma unroll
  for (int r = 0; r < 32; r += 8)
    tile[ty + r][tx] = in[(size_t)(by * 32 + ty + r) * N + bx * 32 + tx];
  __syncthreads();
#pragma unroll
  for (int r = 0; r < 32; r += 8)
    out[(size_t)(bx * 32 + ty + r) * K + by * 32 + tx] = f2bf(tile[tx][ty + r]);
}

// ---------------- LayerNorm: x [rows][1024] f32 -> out bf16 ------------------
__global__ __launch_bounds__(256) void k_layernorm(
    const float* __restrict__ x, const float* __restrict__ gamma,
    const float* __restrict__ beta, u16* __restrict__ out) {
  int row = blockIdx.x, t = threadIdx.x;
  const float4 v = ((const float4*)(x + (size_t)row * 1024))[t];
  float sum = v.x + v.y + v.z + v.w;
  float sq = v.x * v.x + v.y * v.y + v.z * v.z + v.w * v.w;
#pragma unroll
  for (int o = 32; o >= 1; o >>= 1) {
    sum += __shfl_down(sum, o);
    sq += __shfl_down(sq, o);
  }
  __shared__ float red[8];
  if ((t & 63) == 0) { red[(t >> 6) * 2] = sum; red[(t >> 6) * 2 + 1] = sq; }
  __syncthreads();
  sum = red[0] + red[2] + red[4] + red[6];
  sq = red[1] + red[3] + red[5] + red[7];
  float mean = sum * (1.0f / 1024.0f);
  float var = sq * (1.0f / 1024.0f) - mean * mean;
  float rstd = rsqrtf(var + 1e-5f);
  float4 g = ((const float4*)gamma)[t];
  float4 b = ((const float4*)beta)[t];
  ushort4 o4;
  o4.x = f2bf(g.x * (v.x - mean) * rstd + b.x);
  o4.y = f2bf(g.y * (v.y - mean) * rstd + b.y);
  o4.z = f2bf(g.z * (v.z - mean) * rstd + b.z);
  o4.w = f2bf(g.w * (v.w - mean) * rstd + b.w);
  ((ushort4*)(out + (size_t)row * 1024))[t] = o4;
}

// ---------------- epilogues (r = M row; c0 = first of 4 consecutive N) -------
struct EpiQKV {  // scatter qkv: Q,K [B*H][S][64] bf16 ; VT [B*H][64][S] bf16
  u16 *Q, *K2, *VT;
  DEV void operator()(int r, int c0, const f32x4& v) const {
    int three = c0 >> 10, h = (c0 >> 6) & 15, hd = c0 & 63;
    int b = r >> 11, s = r & 2047;
    int bh = b * 16 + h;
    ushort4 o;
    o.x = f2bf(v[0]); o.y = f2bf(v[1]); o.z = f2bf(v[2]); o.w = f2bf(v[3]);
    if (three == 0)
      *(ushort4*)&Q[((size_t)bh * 2048 + s) * 64 + hd] = o;
    else if (three == 1)
      *(ushort4*)&K2[((size_t)bh * 2048 + s) * 64 + hd] = o;
    else {
      VT[((size_t)bh * 64 + hd + 0) * 2048 + s] = o.x;
      VT[((size_t)bh * 64 + hd + 1) * 2048 + s] = o.y;
      VT[((size_t)bh * 64 + hd + 2) * 2048 + s] = o.z;
      VT[((size_t)bh * 64 + hd + 3) * 2048 + s] = o.w;
    }
  }
};

struct EpiBiasResid {  // out f32 = v + bias[c] + resid[r*N+c]
  const float* bias; const float* resid; float* out; int N;
  DEV void operator()(int r, int c0, const f32x4& v) const {
    size_t idx = (size_t)r * N + c0;
    float4 bb = *(const float4*)&bias[c0];
    float4 rr = *(const float4*)&resid[idx];
    float4 o;
    o.x = v[0] + bb.x + rr.x; o.y = v[1] + bb.y + rr.y;
    o.z = v[2] + bb.z + rr.z; o.w = v[3] + bb.w + rr.w;
    *(float4*)&out[idx] = o;
  }
};

struct EpiBiasGelu {  // out bf16 = gelu_tanh(v + bias[c])
  const float* bias; u16* out; int N;
  DEV float gelu(float xx) const {
    float u = 0.7978845608f * (xx + 0.044715f * xx * xx * xx);
    float e = __expf(2.0f * u);
    float th = 1.0f - 2.0f / (e + 1.0f);
    return 0.5f * xx * (1.0f + th);
  }
  DEV void operator()(int r, int c0, const f32x4& v) const {
    float4 bb = *(const float4*)&bias[c0];
    ushort4 o;
    o.x = f2bf(gelu(v[0] + bb.x)); o.y = f2bf(gelu(v[1] + bb.y));
    o.z = f2bf(gelu(v[2] + bb.z)); o.w = f2bf(gelu(v[3] + bb.w));
    *(ushort4*)&out[(size_t)r * N + c0] = o;
  }
};

// ---------------- GEMM TN: A[M,K] bf16 K-contig, Bt[N,K] bf16 K-contig -------
// 128x128 tile, 256 thr (4 waves 2x2), BK=64 as TWO independent 32-K panels.
// Round-0 body, DEPTH-2 double-buffered across 64-K steps:
//   iter T: compute tile T from buf[T&1]  (reads+MFMA, compiler-ordered)
//           BAR; stage tile T+2 -> buf[T&1]; VMW(8) [waits tile T+1, issued a
//           FULL iteration earlier]; BAR
// The only vmcnt wait targets iteration-old loads, so HBM/L2 latency hides
// under the compute phase (prefetch distance 2).  Even a conservative
// compiler-inserted vmcnt before the reads targets the same iteration-old
// loads -> cheap either way.  LDS 64 KB -> 2 blocks/CU.
// Cross-wave visibility: every wave VMW-drains tile T+1 before the iter-end
// BAR, so all slices (staged per-wave) are in LDS before anyone reads them.
// WAR safety: stage into buf[T&1] comes after BAR1; all waves' ds_reads of
// that buffer completed into registers (lgkm waits precede the consuming
// MFMAs) before each wave reached BAR1.
// mfma(bfr, af): lane holds row m = l16, cols n = quad*4 + reg (4 consecutive)
#define STG8(tk, d) do { \
    GLDS(gA + (tk) * 64,                        &As[d][0][t * 8]); \
    GLDS(gA + (tk) * 64 + (size_t)64 * K,       &As[d][0][t * 8 + 2048]); \
    GLDS(gA + (tk) * 64 + 32,                   &As[d][1][t * 8]); \
    GLDS(gA + (tk) * 64 + 32 + (size_t)64 * K,  &As[d][1][t * 8 + 2048]); \
    GLDS(gB + (tk) * 64,                        &Bs[d][0][t * 8]); \
    GLDS(gB + (tk) * 64 + (size_t)64 * K,       &Bs[d][0][t * 8 + 2048]); \
    GLDS(gB + (tk) * 64 + 32,                   &Bs[d][1][t * 8]); \
    GLDS(gB + (tk) * 64 + 32 + (size_t)64 * K,  &Bs[d][1][t * 8 + 2048]); \
  } while (0)

template <typename Epi>
__global__ __launch_bounds__(256) void k_gemm_tn(
    const u16* __restrict__ A, const u16* __restrict__ Bt, int K, Epi epi) {
  __shared__ u16 As[2][2][128 * 32];  // [dbuf][panel][row*32+k], 32 KB
  __shared__ u16 Bs[2][2][128 * 32];  // 32 KB  -> 64 KB total
  const int t = threadIdx.x;
  const int bm = blockIdx.x, bn = blockIdx.y;
  const int lane = t & 63, w = t >> 6;
  const int wm = w >> 1, wn = w & 1;
  const int quad = lane >> 4, l16 = lane & 15;
  f32x4 acc[4][4] = {};
  const u16* gA = A + (size_t)(bm * 128 + (t >> 2)) * K + (t & 3) * 8;
  const u16* gB = Bt + (size_t)(bn * 128 + (t >> 2)) * K + (t & 3) * 8;
  const int NT = K >> 6;  // K % 64 == 0 for all our GEMMs; NT >= 2

  // prologue: tiles 0 and 1 in flight; drain tile 0 (8 oldest), keep tile 1.
  STG8(0, 0);
  STG8(1, 1);
  VMW(8);
  BAR();

  for (int T = 0; T < NT; ++T) {
    const int d = T & 1;
#pragma unroll
    for (int kk = 0; kk < 2; ++kk) {
      bf16x8 af[4], bfr[4];
#pragma unroll
      for (int mt = 0; mt < 4; ++mt)
        af[mt] = *(const bf16x8*)&As[d][kk][(wm * 64 + mt * 16 + l16) * 32 + quad * 8];
#pragma unroll
      for (int nt = 0; nt < 4; ++nt)
        bfr[nt] = *(const bf16x8*)&Bs[d][kk][(wn * 64 + nt * 16 + l16) * 32 + quad * 8];
#pragma unroll
      for (int mt = 0; mt < 4; ++mt)
#pragma unroll
        for (int nt = 0; nt < 4; ++nt)
          acc[mt][nt] = __builtin_amdgcn_mfma_f32_16x16x32_bf16(
              bfr[nt], af[mt], acc[mt][nt], 0, 0, 0);
    }
    SCHED0();   // pin reads/MFMA above the barrier
    BAR();      // all waves done reading buf[d]
    SCHED0();   // pin the stage below the barrier
    if (T + 2 < NT) {
      STG8(T + 2, d);   // overwrite buf[d] with tile T+2
      VMW(8);           // drain tile T+1 (issued one full iteration ago)
    } else {
      VMW(0);           // tail: drain everything before last reads
    }
    BAR();
  }

  const int r0 = bm * 128 + wm * 64 + l16;       // M
  const int c0 = bn * 128 + wn * 64 + quad * 4;  // N (4 consecutive per lane)
#pragma unroll
  for (int mt = 0; mt < 4; ++mt)
#pragma unroll
    for (int nt = 0; nt < 4; ++nt)
      epi(r0 + mt * 16, c0 + nt * 16, acc[mt][nt]);
}

// ---------------- causal flash attention (S^T form, no-max online softmax) ---
// grid (64 bh, 32 qtiles), 256 thr. Q-tile 64 rows; each wave 16 q-rows.
// mfma(kf, qf) -> S^T: lane holds q = l16 (fixed), kpos = quad*4+reg.
#define PW 72  // u16 row stride: 144 B; 2-way banks on b128 reads (free)

__global__ __launch_bounds__(256) void k_attn(
    const u16* __restrict__ Qg, const u16* __restrict__ Kg,
    const u16* __restrict__ VTg, u16* __restrict__ ctx) {
  const int bh = blockIdx.x;
  const int qt = 31 - blockIdx.y;  // big blocks first for tail scheduling
  const int b = bh >> 4, h = bh & 15;
  const int t = threadIdx.x, lane = t & 63, w = t >> 6;
  const int quad = lane >> 4, l16 = lane & 15;
  const int q0 = qt * 64;
  __shared__ u16 Qs[64 * PW], Ks[64 * PW], Vs[64 * PW];
  __shared__ u16 Ps[4][16 * PW];
  __shared__ float l_lds[4][16];
  const u16* Qbase = Qg + (size_t)bh * (2048 * 64);
  const u16* Kbase = Kg + (size_t)bh * (2048 * 64);
  const u16* Vbase = VTg + (size_t)bh * (64 * 2048);
#pragma unroll
  for (int j = 0; j < 4; ++j) {
    int ch = t + 256 * j, r = ch >> 4, cc = (ch & 15) * 4;
    *(u64*)&Qs[r * PW + cc] = *(const u64*)(Qbase + (size_t)(q0 + r) * 64 + cc);
  }
  __syncthreads();
  bf16x8 qf0 = *(const bf16x8*)&Qs[(w * 16 + l16) * PW + quad * 8];
  bf16x8 qf1 = *(const bf16x8*)&Qs[(w * 16 + l16) * PW + 32 + quad * 8];
  const int qrow = q0 + w * 16 + l16;  // one q-row per lane
  const float c1 = 0.18033688011f;     // (1/8) * log2(e)
  float lsum = 0.f;
  f32x4 acco[4] = {};
  for (int kt = 0; kt <= qt; ++kt) {
    const int k0 = kt * 64;
    __syncthreads();
#pragma unroll
    for (int j = 0; j < 4; ++j) {
      int ch = t + 256 * j, r = ch >> 4, cc = (ch & 15) * 4;
      *(u64*)&Ks[r * PW + cc] =
          *(const u64*)(Kbase + (size_t)(k0 + r) * 64 + cc);
      *(u64*)&Vs[r * PW + cc] =
          *(const u64*)(Vbase + (size_t)r * 2048 + k0 + cc);
    }
    __syncthreads();
    f32x4 sacc[4] = {};
#pragma unroll
    for (int kk = 0; kk < 2; ++kk) {
      bf16x8 qf = kk ? qf1 : qf0;
#pragma unroll
      for (int nt = 0; nt < 4; ++nt) {
        bf16x8 kf = *(const bf16x8*)&Ks[(nt * 16 + l16) * PW + kk * 32 + quad * 8];
        sacc[nt] = __builtin_amdgcn_mfma_f32_16x16x32_bf16(kf, qf, sacc[nt], 0, 0, 0);
      }
    }
    const bool diag = (kt == qt);
    float ls = 0.f;
#pragma unroll
    for (int nt = 0; nt < 4; ++nt) {
      ushort4 o;
#pragma unroll
      for (int reg = 0; reg < 4; ++reg) {
        float p = __builtin_amdgcn_exp2f(sacc[nt][reg] * c1);  // bounded scores
        if (diag && (k0 + nt * 16 + quad * 4 + reg > qrow)) p = 0.f;
        ls += p;
        (&o.x)[reg] = f2bf(p);
      }
      *(ushort4*)&Ps[w][l16 * PW + nt * 16 + quad * 4] = o;  // P^T -> A-layout
    }
    ls += __shfl_xor(ls, 16);
    ls += __shfl_xor(ls, 32);
    lsum += ls;
#pragma unroll
    for (int kk = 0; kk < 2; ++kk) {
      bf16x8 pf = *(const bf16x8*)&Ps[w][l16 * PW + kk * 32 + quad * 8];
#pragma unroll
      for (int nt = 0; nt < 4; ++nt) {
        bf16x8 vf = *(const bf16x8*)&Vs[(nt * 16 + l16) * PW + kk * 32 + quad * 8];
        acco[nt] = __builtin_amdgcn_mfma_f32_16x16x32_bf16(pf, vf, acco[nt], 0, 0, 0);
      }
    }
  }
  if (quad == 0) l_lds[w][l16] = lsum;  // same-wave DS ops are ordered
  float4 lv = *(const float4*)&l_lds[w][quad * 4];
  float inv[4];
  inv[0] = 1.0f / lv.x; inv[1] = 1.0f / lv.y;
  inv[2] = 1.0f / lv.z; inv[3] = 1.0f / lv.w;
#pragma unroll
  for (int nt = 0; nt < 4; ++nt)
#pragma unroll
    for (int reg = 0; reg < 4; ++reg) {
      float o = acco[nt][reg] * inv[reg];
      int q = q0 + w * 16 + quad * 4 + reg;
      ctx[((size_t)(b * 2048 + q)) * 1024 + h * 64 + nt * 16 + l16] = f2bf(o);
    }
}

// ---------------- orchestration ----------------------------------------------
extern "C" void kernel_launch(void* const* d_in, const int* in_sizes, int n_in,
                              void* d_out, int out_size, void* d_ws, size_t ws_size,
                              hipStream_t stream) {
  (void)in_sizes; (void)n_in; (void)out_size; (void)ws_size;
  const float* x    = (const float*)d_in[0];
  const float* Wqkv = (const float*)d_in[1];
  const float* Wout = (const float*)d_in[2];
  const float* bout = (const float*)d_in[3];
  const float* W1   = (const float*)d_in[4];
  const float* b1   = (const float*)d_in[5];
  const float* W2   = (const float*)d_in[6];
  const float* b2   = (const float*)d_in[7];
  const float* g1   = (const float*)d_in[8];
  const float* s1   = (const float*)d_in[9];
  const float* g2   = (const float*)d_in[10];
  const float* s2   = (const float*)d_in[11];

  char* ws = (char*)d_ws;
  u16*   WqkvT = (u16*)(ws + 0);           //  6291456 B
  u16*   WoutT = (u16*)(ws + 6291456);     //  2097152
  u16*   W1T   = (u16*)(ws + 8388608);     //  8388608
  u16*   W2T   = (u16*)(ws + 16777216);    //  8388608
  float* x1    = (float*)(ws + 25165824);  // 33554432
  u16*   h12   = (u16*)(ws + 58720256);    // 16777216  (h1, later h2)
  u16*   Qb    = (u16*)(ws + 75497472);    // 16777216
  u16*   Kb    = (u16*)(ws + 92274688);    // 16777216
  u16*   VTb   = (u16*)(ws + 109051904);   // 16777216
  u16*   ctx   = (u16*)(ws + 125829120);   // 16777216  -> total 142606336
  u16*   a1    = (u16*)(ws + 75497472);    // 67108864, aliases Q..ctx (dead)

  k_transpose_all<<<12288, 256, 0, stream>>>(Wqkv, Wout, W1, W2,
                                             WqkvT, WoutT, W1T, W2T);

  k_layernorm<<<8192, 256, 0, stream>>>(x, g1, s1, h12);
  k_gemm_tn<<<dim3(64, 24), 256, 0, stream>>>(h12, WqkvT, 1024,
                                              EpiQKV{Qb, Kb, VTb});
  k_attn<<<dim3(64, 32), 256, 0, stream>>>(Qb, Kb, VTb, ctx);
  k_gemm_tn<<<dim3(64, 8), 256, 0, stream>>>(ctx, WoutT, 1024,
                                             EpiBiasResid{bout, x, x1, 1024});
  k_layernorm<<<8192, 256, 0, stream>>>(x1, g2, s2, h12);
  k_gemm_tn<<<dim3(64, 32), 256, 0, stream>>>(h12, W1T, 1024,
                                              EpiBiasGelu{b1, a1, 4096});
  k_gemm_tn<<<dim3(64, 8), 256, 0, stream>>>(a1, W2T, 4096,
                                             EpiBiasResid{b2, x1, (float*)d_out, 1024});
}

// Round 6
// 516.237 us; speedup vs baseline: 1.1502x; 1.0378x over previous
//
#include <hip/hip_runtime.h>
#include <stdint.h>

typedef unsigned short u16;
typedef unsigned long long u64;
typedef __attribute__((ext_vector_type(8))) short bf16x8;
typedef __attribute__((ext_vector_type(4))) float f32x4;

#define DEV __device__ __forceinline__

DEV u16 f2bf(float f) {
  union { float f; unsigned u; } v; v.f = f;
  unsigned r = (v.u + 0x7fffu + ((v.u >> 16) & 1u)) >> 16;
  return (u16)r;
}

#define GLDS(g, l) __builtin_amdgcn_global_load_lds( \
    (const __attribute__((address_space(1))) void*)(g), \
    (__attribute__((address_space(3))) void*)(l), 16, 0, 0)

#define BAR() __builtin_amdgcn_s_barrier()
#define LGKM0() asm volatile("s_waitcnt lgkmcnt(0)" ::: "memory")
#define VMW(n) asm volatile("s_waitcnt vmcnt(" #n ")" ::: "memory")
#define SCHED0() __builtin_amdgcn_sched_barrier(0)

// ------- fused weight transpose+cast: [K][N] f32 -> [N][K] bf16, 4 segments --
__global__ __launch_bounds__(256) void k_transpose_all(
    const float* __restrict__ Wqkv, const float* __restrict__ Wout,
    const float* __restrict__ W1, const float* __restrict__ W2,
    u16* __restrict__ WqkvT, u16* __restrict__ WoutT,
    u16* __restrict__ W1T, u16* __restrict__ W2T) {
  int id = blockIdx.x;
  const float* in; u16* out; int K, N, nx, base;
  if (id < 3072)      { in = Wqkv; out = WqkvT; K = 1024; N = 3072; nx = 96;  base = 0; }
  else if (id < 4096) { in = Wout; out = WoutT; K = 1024; N = 1024; nx = 32;  base = 3072; }
  else if (id < 8192) { in = W1;   out = W1T;   K = 1024; N = 4096; nx = 128; base = 4096; }
  else                { in = W2;   out = W2T;   K = 4096; N = 1024; nx = 32;  base = 8192; }
  int seg = id - base, bx = seg % nx, by = seg / nx;
  __shared__ float tile[32][33];
  int tx = threadIdx.x & 31, ty = threadIdx.x >> 5;  // 32 x 8
#pragma unroll
  for (int r = 0; r < 32; r += 8)
    tile[ty + r][tx] = in[(size_t)(by * 32 + ty + r) * N + bx * 32 + tx];
  __syncthreads();
#pragma unroll
  for (int r = 0; r < 32; r += 8)
    out[(size_t)(bx * 32 + ty + r) * K + by * 32 + tx] = f2bf(tile[tx][ty + r]);
}

// ---------------- LayerNorm: x [rows][1024] f32 -> out bf16 ------------------
__global__ __launch_bounds__(256) void k_layernorm(
    const float* __restrict__ x, const float* __restrict__ gamma,
    const float* __restrict__ beta, u16* __restrict__ out) {
  int row = blockIdx.x, t = threadIdx.x;
  const float4 v = ((const float4*)(x + (size_t)row * 1024))[t];
  float sum = v.x + v.y + v.z + v.w;
  float sq = v.x * v.x + v.y * v.y + v.z * v.z + v.w * v.w;
#pragma unroll
  for (int o = 32; o >= 1; o >>= 1) {
    sum += __shfl_down(sum, o);
    sq += __shfl_down(sq, o);
  }
  __shared__ float red[8];
  if ((t & 63) == 0) { red[(t >> 6) * 2] = sum; red[(t >> 6) * 2 + 1] = sq; }
  __syncthreads();
  sum = red[0] + red[2] + red[4] + red[6];
  sq = red[1] + red[3] + red[5] + red[7];
  float mean = sum * (1.0f / 1024.0f);
  float var = sq * (1.0f / 1024.0f) - mean * mean;
  float rstd = rsqrtf(var + 1e-5f);
  float4 g = ((const float4*)gamma)[t];
  float4 b = ((const float4*)beta)[t];
  ushort4 o4;
  o4.x = f2bf(g.x * (v.x - mean) * rstd + b.x);
  o4.y = f2bf(g.y * (v.y - mean) * rstd + b.y);
  o4.z = f2bf(g.z * (v.z - mean) * rstd + b.z);
  o4.w = f2bf(g.w * (v.w - mean) * rstd + b.w);
  ((ushort4*)(out + (size_t)row * 1024))[t] = o4;
}

// ---------------- epilogues (r = M row; c0 = first of 4 consecutive N) -------
struct EpiQKV {  // scatter qkv: Q,K [B*H][S][64] bf16 ; VT [B*H][64][S] bf16
  u16 *Q, *K2, *VT;
  DEV void operator()(int r, int c0, const f32x4& v) const {
    int three = c0 >> 10, h = (c0 >> 6) & 15, hd = c0 & 63;
    int b = r >> 11, s = r & 2047;
    int bh = b * 16 + h;
    ushort4 o;
    o.x = f2bf(v[0]); o.y = f2bf(v[1]); o.z = f2bf(v[2]); o.w = f2bf(v[3]);
    if (three == 0)
      *(ushort4*)&Q[((size_t)bh * 2048 + s) * 64 + hd] = o;
    else if (three == 1)
      *(ushort4*)&K2[((size_t)bh * 2048 + s) * 64 + hd] = o;
    else {
      VT[((size_t)bh * 64 + hd + 0) * 2048 + s] = o.x;
      VT[((size_t)bh * 64 + hd + 1) * 2048 + s] = o.y;
      VT[((size_t)bh * 64 + hd + 2) * 2048 + s] = o.z;
      VT[((size_t)bh * 64 + hd + 3) * 2048 + s] = o.w;
    }
  }
};

struct EpiBiasResid {  // out f32 = v + bias[c] + resid[r*N+c]
  const float* bias; const float* resid; float* out; int N;
  DEV void operator()(int r, int c0, const f32x4& v) const {
    size_t idx = (size_t)r * N + c0;
    float4 bb = *(const float4*)&bias[c0];
    float4 rr = *(const float4*)&resid[idx];
    float4 o;
    o.x = v[0] + bb.x + rr.x; o.y = v[1] + bb.y + rr.y;
    o.z = v[2] + bb.z + rr.z; o.w = v[3] + bb.w + rr.w;
    *(float4*)&out[idx] = o;
  }
};

struct EpiBiasGelu {  // out bf16 = gelu_tanh(v + bias[c])
  const float* bias; u16* out; int N;
  DEV float gelu(float xx) const {
    float u = 0.7978845608f * (xx + 0.044715f * xx * xx * xx);
    float e = __expf(2.0f * u);
    float th = 1.0f - 2.0f / (e + 1.0f);
    return 0.5f * xx * (1.0f + th);
  }
  DEV void operator()(int r, int c0, const f32x4& v) const {
    float4 bb = *(const float4*)&bias[c0];
    ushort4 o;
    o.x = f2bf(gelu(v[0] + bb.x)); o.y = f2bf(gelu(v[1] + bb.y));
    o.z = f2bf(gelu(v[2] + bb.z)); o.w = f2bf(gelu(v[3] + bb.w));
    *(ushort4*)&out[(size_t)r * N + c0] = o;
  }
};

// ---------------- GEMM TN: A[M,K] bf16 K-contig, Bt[N,K] bf16 K-contig -------
// 128x128 tile, 256 thr (4 waves 2x2), BK=64 as TWO independent 32-K panels.
// DEPTH-2 double-buffered across 64-K steps (round-5 verified best).
#define STG8(tk, d) do { \
    GLDS(gA + (tk) * 64,                        &As[d][0][t * 8]); \
    GLDS(gA + (tk) * 64 + (size_t)64 * K,       &As[d][0][t * 8 + 2048]); \
    GLDS(gA + (tk) * 64 + 32,                   &As[d][1][t * 8]); \
    GLDS(gA + (tk) * 64 + 32 + (size_t)64 * K,  &As[d][1][t * 8 + 2048]); \
    GLDS(gB + (tk) * 64,                        &Bs[d][0][t * 8]); \
    GLDS(gB + (tk) * 64 + (size_t)64 * K,       &Bs[d][0][t * 8 + 2048]); \
    GLDS(gB + (tk) * 64 + 32,                   &Bs[d][1][t * 8]); \
    GLDS(gB + (tk) * 64 + 32 + (size_t)64 * K,  &Bs[d][1][t * 8 + 2048]); \
  } while (0)

template <typename Epi>
__global__ __launch_bounds__(256) void k_gemm_tn(
    const u16* __restrict__ A, const u16* __restrict__ Bt, int K, Epi epi) {
  __shared__ u16 As[2][2][128 * 32];  // [dbuf][panel][row*32+k], 32 KB
  __shared__ u16 Bs[2][2][128 * 32];  // 32 KB  -> 64 KB total
  const int t = threadIdx.x;
  const int bm = blockIdx.x, bn = blockIdx.y;
  const int lane = t & 63, w = t >> 6;
  const int wm = w >> 1, wn = w & 1;
  const int quad = lane >> 4, l16 = lane & 15;
  f32x4 acc[4][4] = {};
  const u16* gA = A + (size_t)(bm * 128 + (t >> 2)) * K + (t & 3) * 8;
  const u16* gB = Bt + (size_t)(bn * 128 + (t >> 2)) * K + (t & 3) * 8;
  const int NT = K >> 6;  // K % 64 == 0 for all our GEMMs; NT >= 2

  STG8(0, 0);
  STG8(1, 1);
  VMW(8);
  BAR();

  for (int T = 0; T < NT; ++T) {
    const int d = T & 1;
#pragma unroll
    for (int kk = 0; kk < 2; ++kk) {
      bf16x8 af[4], bfr[4];
#pragma unroll
      for (int mt = 0; mt < 4; ++mt)
        af[mt] = *(const bf16x8*)&As[d][kk][(wm * 64 + mt * 16 + l16) * 32 + quad * 8];
#pragma unroll
      for (int nt = 0; nt < 4; ++nt)
        bfr[nt] = *(const bf16x8*)&Bs[d][kk][(wn * 64 + nt * 16 + l16) * 32 + quad * 8];
#pragma unroll
      for (int mt = 0; mt < 4; ++mt)
#pragma unroll
        for (int nt = 0; nt < 4; ++nt)
          acc[mt][nt] = __builtin_amdgcn_mfma_f32_16x16x32_bf16(
              bfr[nt], af[mt], acc[mt][nt], 0, 0, 0);
    }
    SCHED0();
    BAR();      // all waves done reading buf[d]
    SCHED0();
    if (T + 2 < NT) {
      STG8(T + 2, d);   // overwrite buf[d] with tile T+2
      VMW(8);           // drain tile T+1 (issued one full iteration ago)
    } else {
      VMW(0);           // tail
    }
    BAR();
  }

  const int r0 = bm * 128 + wm * 64 + l16;       // M
  const int c0 = bn * 128 + wn * 64 + quad * 4;  // N (4 consecutive per lane)
#pragma unroll
  for (int mt = 0; mt < 4; ++mt)
#pragma unroll
    for (int nt = 0; nt < 4; ++nt)
      epi(r0 + mt * 16, c0 + nt * 16, acc[mt][nt]);
}

// ---------------- causal flash attention (S^T form, no-max online softmax) ---
// grid (64 bh, 32 qtiles), 256 thr. Q-tile 64 rows; each wave 16 q-rows.
// T14 async-STAGE split: K/V(kt+1) global->reg loads issue during tile kt's
// compute; VMW(0) lands them at the next write point (~500+ cy later).  Two
// NAMED reg sets (a/b) unrolled 2-deep (rule #20: no runtime-indexed regs).
// Raw BAR() (not __syncthreads -- which would drain vmcnt and kill the
// pipeline); LGKM0 before BAR makes ds_writes visible to other waves.  WAR on
// Ks/Vs: each wave's ds_reads are consumed by its MFMAs before it reaches the
// next BAR.  All barriers uniform (bounds depend only on uniform qt).
#define PW 72  // u16 row stride: 144 B; 2-way banks on b128 reads (free)

#define ATT_LOAD(kr, vr, k0_) do { \
  _Pragma("unroll") for (int j = 0; j < 4; ++j) { \
    int ch = t + 256 * j, r = ch >> 4, cc = (ch & 15) * 4; \
    kr[j] = *(const u64*)(Kbase + (size_t)((k0_) + r) * 64 + cc); \
    vr[j] = *(const u64*)(Vbase + (size_t)r * 2048 + (k0_) + cc); \
  } } while (0)

#define ATT_WRITE(kr, vr) do { \
  _Pragma("unroll") for (int j = 0; j < 4; ++j) { \
    int ch = t + 256 * j, r = ch >> 4, cc = (ch & 15) * 4; \
    *(u64*)&Ks[r * PW + cc] = kr[j]; \
    *(u64*)&Vs[r * PW + cc] = vr[j]; \
  } } while (0)

__global__ __launch_bounds__(256) void k_attn(
    const u16* __restrict__ Qg, const u16* __restrict__ Kg,
    const u16* __restrict__ VTg, u16* __restrict__ ctx) {
  const int bh = blockIdx.x;
  const int qt = 31 - blockIdx.y;  // big blocks first for tail scheduling
  const int b = bh >> 4, h = bh & 15;
  const int t = threadIdx.x, lane = t & 63, w = t >> 6;
  const int quad = lane >> 4, l16 = lane & 15;
  const int q0 = qt * 64;
  __shared__ u16 Qs[64 * PW], Ks[64 * PW], Vs[64 * PW];
  __shared__ u16 Ps[4][16 * PW];
  __shared__ float l_lds[4][16];
  const u16* Qbase = Qg + (size_t)bh * (2048 * 64);
  const u16* Kbase = Kg + (size_t)bh * (2048 * 64);
  const u16* Vbase = VTg + (size_t)bh * (64 * 2048);
#pragma unroll
  for (int j = 0; j < 4; ++j) {
    int ch = t + 256 * j, r = ch >> 4, cc = (ch & 15) * 4;
    *(u64*)&Qs[r * PW + cc] = *(const u64*)(Qbase + (size_t)(q0 + r) * 64 + cc);
  }
  __syncthreads();
  bf16x8 qf0 = *(const bf16x8*)&Qs[(w * 16 + l16) * PW + quad * 8];
  bf16x8 qf1 = *(const bf16x8*)&Qs[(w * 16 + l16) * PW + 32 + quad * 8];
  const int qrow = q0 + w * 16 + l16;  // one q-row per lane
  const float c1 = 0.18033688011f;     // (1/8) * log2(e)
  float lsum = 0.f;
  f32x4 acco[4] = {};

  auto tile = [&](int kt) {
    const int k0 = kt * 64;
    f32x4 sacc[4] = {};
#pragma unroll
    for (int kk = 0; kk < 2; ++kk) {
      bf16x8 qf = kk ? qf1 : qf0;
#pragma unroll
      for (int nt = 0; nt < 4; ++nt) {
        bf16x8 kf = *(const bf16x8*)&Ks[(nt * 16 + l16) * PW + kk * 32 + quad * 8];
        sacc[nt] = __builtin_amdgcn_mfma_f32_16x16x32_bf16(kf, qf, sacc[nt], 0, 0, 0);
      }
    }
    const bool diag = (kt == qt);
    float ls = 0.f;
#pragma unroll
    for (int nt = 0; nt < 4; ++nt) {
      ushort4 o;
#pragma unroll
      for (int reg = 0; reg < 4; ++reg) {
        float p = __builtin_amdgcn_exp2f(sacc[nt][reg] * c1);  // bounded scores
        if (diag && (k0 + nt * 16 + quad * 4 + reg > qrow)) p = 0.f;
        ls += p;
        (&o.x)[reg] = f2bf(p);
      }
      *(ushort4*)&Ps[w][l16 * PW + nt * 16 + quad * 4] = o;  // P^T -> A-layout
    }
    ls += __shfl_xor(ls, 16);
    ls += __shfl_xor(ls, 32);
    lsum += ls;
#pragma unroll
    for (int kk = 0; kk < 2; ++kk) {
      bf16x8 pf = *(const bf16x8*)&Ps[w][l16 * PW + kk * 32 + quad * 8];
#pragma unroll
      for (int nt = 0; nt < 4; ++nt) {
        bf16x8 vf = *(const bf16x8*)&Vs[(nt * 16 + l16) * PW + kk * 32 + quad * 8];
        acco[nt] = __builtin_amdgcn_mfma_f32_16x16x32_bf16(pf, vf, acco[nt], 0, 0, 0);
      }
    }
  };

  u64 kra[4], vra[4], krb[4], vrb[4];
  ATT_LOAD(kra, vra, 0);
  int kt = 0;
  while (true) {
    VMW(0);             // set-a data landed (issued a full tile earlier)
    BAR();              // all waves done reading Ks/Vs from prev tile
    ATT_WRITE(kra, vra);
    if (kt + 1 <= qt) ATT_LOAD(krb, vrb, (kt + 1) * 64);  // prefetch, in flight
    LGKM0();            // ds_writes visible
    BAR();
    tile(kt);
    if (++kt > qt) break;
    VMW(0);
    BAR();
    ATT_WRITE(krb, vrb);
    if (kt + 1 <= qt) ATT_LOAD(kra, vra, (kt + 1) * 64);
    LGKM0();
    BAR();
    tile(kt);
    if (++kt > qt) break;
  }

  if (quad == 0) l_lds[w][l16] = lsum;  // same-wave DS ops are ordered
  float4 lv = *(const float4*)&l_lds[w][quad * 4];
  float inv[4];
  inv[0] = 1.0f / lv.x; inv[1] = 1.0f / lv.y;
  inv[2] = 1.0f / lv.z; inv[3] = 1.0f / lv.w;
#pragma unroll
  for (int nt = 0; nt < 4; ++nt)
#pragma unroll
    for (int reg = 0; reg < 4; ++reg) {
      float o = acco[nt][reg] * inv[reg];
      int q = q0 + w * 16 + quad * 4 + reg;
      ctx[((size_t)(b * 2048 + q)) * 1024 + h * 64 + nt * 16 + l16] = f2bf(o);
    }
}

// ---------------- orchestration ----------------------------------------------
extern "C" void kernel_launch(void* const* d_in, const int* in_sizes, int n_in,
                              void* d_out, int out_size, void* d_ws, size_t ws_size,
                              hipStream_t stream) {
  (void)in_sizes; (void)n_in; (void)out_size; (void)ws_size;
  const float* x    = (const float*)d_in[0];
  const float* Wqkv = (const float*)d_in[1];
  const float* Wout = (const float*)d_in[2];
  const float* bout = (const float*)d_in[3];
  const float* W1   = (const float*)d_in[4];
  const float* b1   = (const float*)d_in[5];
  const float* W2   = (const float*)d_in[6];
  const float* b2   = (const float*)d_in[7];
  const float* g1   = (const float*)d_in[8];
  const float* s1   = (const float*)d_in[9];
  const float* g2   = (const float*)d_in[10];
  const float* s2   = (const float*)d_in[11];

  char* ws = (char*)d_ws;
  u16*   WqkvT = (u16*)(ws + 0);           //  6291456 B
  u16*   WoutT = (u16*)(ws + 6291456);     //  2097152
  u16*   W1T   = (u16*)(ws + 8388608);     //  8388608
  u16*   W2T   = (u16*)(ws + 16777216);    //  8388608
  float* x1    = (float*)(ws + 25165824);  // 33554432
  u16*   h12   = (u16*)(ws + 58720256);    // 16777216  (h1, later h2)
  u16*   Qb    = (u16*)(ws + 75497472);    // 16777216
  u16*   Kb    = (u16*)(ws + 92274688);    // 16777216
  u16*   VTb   = (u16*)(ws + 109051904);   // 16777216
  u16*   ctx   = (u16*)(ws + 125829120);   // 16777216  -> total 142606336
  u16*   a1    = (u16*)(ws + 75497472);    // 67108864, aliases Q..ctx (dead)

  k_transpose_all<<<12288, 256, 0, stream>>>(Wqkv, Wout, W1, W2,
                                             WqkvT, WoutT, W1T, W2T);

  k_layernorm<<<8192, 256, 0, stream>>>(x, g1, s1, h12);
  k_gemm_tn<<<dim3(64, 24), 256, 0, stream>>>(h12, WqkvT, 1024,
                                              EpiQKV{Qb, Kb, VTb});
  k_attn<<<dim3(64, 32), 256, 0, stream>>>(Qb, Kb, VTb, ctx);
  k_gemm_tn<<<dim3(64, 8), 256, 0, stream>>>(ctx, WoutT, 1024,
                                             EpiBiasResid{bout, x, x1, 1024});
  k_layernorm<<<8192, 256, 0, stream>>>(x1, g2, s2, h12);
  k_gemm_tn<<<dim3(64, 32), 256, 0, stream>>>(h12, W1T, 1024,
                                              EpiBiasGelu{b1, a1, 4096});
  k_gemm_tn<<<dim3(64, 8), 256, 0, stream>>>(a1, W2T, 4096,
                                             EpiBiasResid{b2, x1, (float*)d_out, 1024});
}